// Round 2
// baseline (190.477 us; speedup 1.0000x reference)
//
#include <hip/hip_runtime.h>
#include <hip/hip_bf16.h>
#include <cmath>

#define ENTRIES 27
#define ACTION  4096
#define BATCH   8192
#define SDIM    322
#define KPAD    352      // 322 padded to multiple of 32
#define NNODES  256

typedef unsigned short u16;
typedef u16 u16x4 __attribute__((ext_vector_type(4)));
typedef u16 u16x8 __attribute__((ext_vector_type(8)));
typedef __bf16 bf16x8 __attribute__((ext_vector_type(8)));
typedef float floatx4 __attribute__((ext_vector_type(4)));

__device__ __forceinline__ u16 f2bf(float f) {
    unsigned u = __builtin_bit_cast(unsigned, f);
    unsigned r = (u + 0x7FFFu + ((u >> 16) & 1u)) >> 16;   // RNE
    return (u16)r;
}

// async global->LDS, 16 B per lane; LDS dest = wave-uniform base + lane*16
__device__ __forceinline__ void gl_lds16(const u16* g, u16* l) {
    __builtin_amdgcn_global_load_lds(
        (const __attribute__((address_space(1))) unsigned int*)g,
        (__attribute__((address_space(3))) unsigned int*)l, 16, 0, 0);
}

// ---------------------------------------------------------------------------
// Build dense Wg[256, KPAD] bf16: Wg[n, idx[n,e]] += W[n,e] (duplicates sum).
// 8 blocks x 256 threads; 32 nodes/block accumulated in LDS f32.
// ---------------------------------------------------------------------------
__global__ __launch_bounds__(256) void build_wg(
    const float* __restrict__ W, const int* __restrict__ idx,
    u16* __restrict__ wg)
{
    __shared__ float rows[32 * KPAD];              // 45056 B
    const int tid = threadIdx.x;
    for (int i = tid; i < 32 * KPAD; i += 256) rows[i] = 0.f;
    __syncthreads();
    if (tid < 32) {
        const int n = blockIdx.x * 32 + tid;
        for (int e = 0; e < ENTRIES; e++)
            rows[tid * KPAD + idx[n * ENTRIES + e]] += W[n * ENTRIES + e];
    }
    __syncthreads();
    for (int i = tid; i < 32 * KPAD; i += 256)
        wg[(size_t)blockIdx.x * 32 * KPAD + i] = f2bf(rows[i]);
}

// ---------------------------------------------------------------------------
// state f32 [8192, 322] -> bf16 [8192, KPAD], zero-padded cols 322..351
// ---------------------------------------------------------------------------
__global__ __launch_bounds__(256) void conv_state(
    const float* __restrict__ s, u16* __restrict__ o)
{
    const int i = blockIdx.x * 256 + threadIdx.x;      // over 8192*352
    const int b = i / KPAD;
    const int c = i - b * KPAD;
    float v = (c < SDIM) ? s[(size_t)b * SDIM + c] : 0.f;
    o[i] = f2bf(v);
}

// ---------------------------------------------------------------------------
// Wf f32 [4096,256] -> bf16 (same layout)
// ---------------------------------------------------------------------------
__global__ __launch_bounds__(256) void conv_wf(
    const float* __restrict__ wf, u16* __restrict__ out)
{
    const int i0 = (blockIdx.x * 256 + threadIdx.x) * 4;
    floatx4 v = *(const floatx4*)(wf + i0);
    u16x4 r;
    r.x = f2bf(v.x); r.y = f2bf(v.y); r.z = f2bf(v.z); r.w = f2bf(v.w);
    *(u16x4*)(out + i0) = r;
}

// ---------------------------------------------------------------------------
// GEMM: C[m,n] = f( sum_k A[m,k]*B[n,k] )  (both operands K-major bf16)
// 128x128 tile, BK=32, 4 waves of 64x64, mfma_f32_16x16x32_bf16,
// global_load_lds width-16 staging (m97 structure).
// EPI=0: out f32 [.., ACTION] = 500*sigmoid(acc)
// EPI=1: out bf16 [.., NNODES] = tanh(acc + bias[n])
// ---------------------------------------------------------------------------
template<int KDIM, int EPI>
__global__ __launch_bounds__(256) void gemm_mfma(
    const u16* __restrict__ A, const u16* __restrict__ B,
    void* __restrict__ outp, const float* __restrict__ bias)
{
    __shared__ u16 As[128 * 32];
    __shared__ u16 Bs[128 * 32];

    const int bm   = blockIdx.x;
    const int bn   = blockIdx.y;
    const int tid  = threadIdx.x;
    const int lane = tid & 63;
    const int wave = tid >> 6;
    const int wm   = wave & 1;
    const int wn   = wave >> 1;
    const int l15  = lane & 15;
    const int koff = (lane >> 4) << 3;

    floatx4 acc[4][4];
#pragma unroll
    for (int mi = 0; mi < 4; mi++)
#pragma unroll
        for (int ni = 0; ni < 4; ni++)
            acc[mi][ni] = (floatx4){0.f, 0.f, 0.f, 0.f};

    // staging addressing: wave handles rows [32*wave, 32*wave+32) of each tile
    // chunk = 16 rows x 32 cols = 1024 B; lane l -> row +(l>>2), col (l&3)*8
    const int srow = wave * 32 + (lane >> 2);
    const int ksub = (lane & 3) << 3;
    const u16* ga = A + ((size_t)bm * 128 + srow) * KDIM + ksub;
    const u16* gb = B + ((size_t)bn * 128 + srow) * KDIM + ksub;
    u16* la = &As[(wave * 32) * 32];
    u16* lb = &Bs[(wave * 32) * 32];

    for (int kk = 0; kk < KDIM; kk += 32) {
        __syncthreads();
        gl_lds16(ga + kk,                  la);
        gl_lds16(ga + kk + 16 * KDIM,      la + 16 * 32);
        gl_lds16(gb + kk,                  lb);
        gl_lds16(gb + kk + 16 * KDIM,      lb + 16 * 32);
        __syncthreads();   // drains vmcnt -> LDS writes visible

        bf16x8 af[4], bf[4];
#pragma unroll
        for (int mi = 0; mi < 4; mi++)
            af[mi] = __builtin_bit_cast(bf16x8,
                *(const u16x8*)&As[((wm << 6) + (mi << 4) + l15) * 32 + koff]);
#pragma unroll
        for (int ni = 0; ni < 4; ni++)
            bf[ni] = __builtin_bit_cast(bf16x8,
                *(const u16x8*)&Bs[((wn << 6) + (ni << 4) + l15) * 32 + koff]);

#pragma unroll
        for (int mi = 0; mi < 4; mi++)
#pragma unroll
            for (int ni = 0; ni < 4; ni++)
                acc[mi][ni] = __builtin_amdgcn_mfma_f32_16x16x32_bf16(
                    af[mi], bf[ni], acc[mi][ni], 0, 0, 0);
    }

    // epilogue: C/D layout col=lane&15, row=(lane>>4)*4+reg
    const int r0 = (lane >> 4) << 2;
    float bv[4];
    if (EPI == 1) {
#pragma unroll
        for (int ni = 0; ni < 4; ni++)
            bv[ni] = bias[bn * 128 + wn * 64 + ni * 16 + l15];
    }
#pragma unroll
    for (int mi = 0; mi < 4; mi++) {
#pragma unroll
        for (int ni = 0; ni < 4; ni++) {
            const int row = bm * 128 + wm * 64 + mi * 16 + r0;
            const int col = bn * 128 + wn * 64 + ni * 16 + l15;
#pragma unroll
            for (int r = 0; r < 4; r++) {
                float v = acc[mi][ni][r];
                if (EPI == 0) {
                    ((float*)outp)[(size_t)(row + r) * ACTION + col] =
                        500.0f / (1.0f + __expf(-v));
                } else {
                    ((u16*)outp)[(size_t)(row + r) * NNODES + col] =
                        f2bf(tanhf(v + bv[ni]));
                }
            }
        }
    }
}

extern "C" void kernel_launch(void* const* d_in, const int* in_sizes, int n_in,
                              void* d_out, int out_size, void* d_ws, size_t ws_size,
                              hipStream_t stream) {
    const float* state = (const float*)d_in[0];
    const float* W     = (const float*)d_in[1];
    const float* b     = (const float*)d_in[2];
    const float* Wf    = (const float*)d_in[3];
    const int*   idx   = (const int*)  d_in[4];
    float* out = (float*)d_out;

    u16* sbf = (u16*)d_ws;                         // 8192*352 bf16
    u16* wg  = sbf + (size_t)BATCH * KPAD;         // 256*352
    u16* y   = wg  + (size_t)NNODES * KPAD;        // 8192*256
    u16* wfb = y   + (size_t)BATCH * NNODES;       // 4096*256

    build_wg  <<<NNODES / 32, 256, 0, stream>>>(W, idx, wg);
    conv_state<<<BATCH * KPAD / 256, 256, 0, stream>>>(state, sbf);
    conv_wf   <<<ACTION * NNODES / 1024, 256, 0, stream>>>(Wf, wfb);
    gemm_mfma<KPAD, 1><<<dim3(BATCH / 128, NNODES / 128), 256, 0, stream>>>(
        sbf, wg, (void*)y, b);
    gemm_mfma<256, 0><<<dim3(BATCH / 128, ACTION / 128), 256, 0, stream>>>(
        y, wfb, (void*)out, nullptr);
}

// Round 3
// 182.213 us; speedup vs baseline: 1.0454x; 1.0454x over previous
//
#include <hip/hip_runtime.h>
#include <hip/hip_bf16.h>
#include <cmath>

#define ENTRIES 27
#define ACTION  4096
#define BATCH   8192
#define SDIM    322
#define KPAD    352      // 322 padded to multiple of 32
#define NNODES  256

typedef unsigned short u16;
typedef u16 u16x4 __attribute__((ext_vector_type(4)));
typedef u16 u16x8 __attribute__((ext_vector_type(8)));
typedef __bf16 bf16x8 __attribute__((ext_vector_type(8)));
typedef float floatx4 __attribute__((ext_vector_type(4)));

__device__ __forceinline__ u16 f2bf(float f) {
    unsigned u = __builtin_bit_cast(unsigned, f);
    unsigned r = (u + 0x7FFFu + ((u >> 16) & 1u)) >> 16;   // RNE
    return (u16)r;
}

// fast 500*sigmoid(v): v_exp + v_rcp instead of precise-division sequence
__device__ __forceinline__ float sig500(float v) {
    return __fdividef(500.0f, 1.0f + __expf(-v));
}
// fast tanh: 1 - 2/(e^{2x}+1)
__device__ __forceinline__ float ftanh(float x) {
    return 1.0f - __fdividef(2.0f, __expf(2.0f * x) + 1.0f);
}

// async global->LDS, 16 B per lane; LDS dest = wave-uniform base + lane*16
__device__ __forceinline__ void gl_lds16(const u16* g, u16* l) {
    __builtin_amdgcn_global_load_lds(
        (const __attribute__((address_space(1))) unsigned int*)g,
        (__attribute__((address_space(3))) unsigned int*)l, 16, 0, 0);
}

// ---------------------------------------------------------------------------
// Build dense Wg[256, KPAD] bf16: Wg[n, idx[n,e]] += W[n,e] (duplicates sum).
// 32 blocks x 256 threads, 8 nodes/block; scatter parallel via LDS atomicAdd.
// ---------------------------------------------------------------------------
__global__ __launch_bounds__(256) void build_wg(
    const float* __restrict__ W, const int* __restrict__ idx,
    u16* __restrict__ wg)
{
    __shared__ float rows[8 * KPAD];               // 11264 B
    const int tid = threadIdx.x;
    for (int i = tid; i < 8 * KPAD; i += 256) rows[i] = 0.f;
    __syncthreads();
    if (tid < 8 * ENTRIES) {                       // 216 active
        const int nl = tid / ENTRIES;
        const int e  = tid - nl * ENTRIES;
        const int n  = blockIdx.x * 8 + nl;
        atomicAdd(&rows[nl * KPAD + idx[n * ENTRIES + e]], W[n * ENTRIES + e]);
    }
    __syncthreads();
    for (int i = tid; i < 8 * KPAD; i += 256)
        wg[(size_t)blockIdx.x * 8 * KPAD + i] = f2bf(rows[i]);
}

// ---------------------------------------------------------------------------
// state f32 [8192, 322] -> bf16 [8192, KPAD], zero-padded; 4 cols/thread
// ---------------------------------------------------------------------------
__global__ __launch_bounds__(256) void conv_state(
    const float* __restrict__ s, u16* __restrict__ o)
{
    const int t   = blockIdx.x * 256 + threadIdx.x;  // over 8192 * 88
    const int row = t / 88;
    const int c0  = (t - row * 88) * 4;
    const float* sp = s + (size_t)row * SDIM;
    u16x4 r;
#pragma unroll
    for (int q = 0; q < 4; q++) {
        const int c = c0 + q;
        float v = (c < SDIM) ? sp[c] : 0.f;
        ((u16*)&r)[q] = f2bf(v);
    }
    *(u16x4*)(o + (size_t)row * KPAD + c0) = r;
}

// ---------------------------------------------------------------------------
// Wf f32 [4096,256] -> bf16 (same layout)
// ---------------------------------------------------------------------------
__global__ __launch_bounds__(256) void conv_wf(
    const float* __restrict__ wf, u16* __restrict__ out)
{
    const int i0 = (blockIdx.x * 256 + threadIdx.x) * 4;
    floatx4 v = *(const floatx4*)(wf + i0);
    u16x4 r;
    r.x = f2bf(v.x); r.y = f2bf(v.y); r.z = f2bf(v.z); r.w = f2bf(v.w);
    *(u16x4*)(out + i0) = r;
}

// ---------------------------------------------------------------------------
// GEMM: C[m,n] = f( sum_k A[m,k]*B[n,k] ), both K-major bf16.
// Tile 128 x BN, BK=32, 4 waves as 2x2 (each 64 x BN/2),
// mfma_f32_16x16x32_bf16, global_load_lds width-16 staging (m97 structure).
// EPI=0: f32 out [.., ACTION] = 500*sigmoid(acc)
// EPI=1: bf16 out [.., NNODES] = tanh(acc + bias[n])
// ---------------------------------------------------------------------------
template<int KDIM, int EPI, int BN>
__global__ __launch_bounds__(256) void gemm_mfma(
    const u16* __restrict__ A, const u16* __restrict__ B,
    void* __restrict__ outp, const float* __restrict__ bias)
{
    constexpr int NI  = BN / 32;         // per-wave 16-col tiles (2 n-waves)
    constexpr int WN  = BN / 2;          // per-wave n extent
    constexpr int ACH = 8;               // A chunks of 1024 B (128 rows x 64 B)
    constexpr int BCH = BN / 16;         // B chunks

    __shared__ u16 As[128 * 32];
    __shared__ u16 Bs[BN * 32];

    const int bm   = blockIdx.x;
    const int bn   = blockIdx.y;
    const int tid  = threadIdx.x;
    const int lane = tid & 63;
    const int wave = tid >> 6;
    const int wm   = wave & 1;
    const int wn   = wave >> 1;
    const int l15  = lane & 15;
    const int koff = (lane >> 4) << 3;

    floatx4 acc[4][NI];
#pragma unroll
    for (int mi = 0; mi < 4; mi++)
#pragma unroll
        for (int ni = 0; ni < NI; ni++)
            acc[mi][ni] = (floatx4){0.f, 0.f, 0.f, 0.f};

    // staging: chunk = 16 rows x 32 cols = 1024 B; lane -> row +(l>>2), k (l&3)*8
    const int crow = lane >> 2;
    const int ckel = (lane & 3) << 3;

    for (int kk = 0; kk < KDIM; kk += 32) {
        __syncthreads();
#pragma unroll
        for (int c = wave; c < ACH + BCH; c += 4) {
            const bool isA = c < ACH;
            const int  cr  = isA ? c : c - ACH;
            const int  row = cr * 16 + crow;
            const u16* g = isA
                ? (A + ((size_t)bm * 128 + row) * KDIM + kk + ckel)
                : (B + ((size_t)bn * BN  + row) * KDIM + kk + ckel);
            u16* l = isA ? &As[cr * 512] : &Bs[cr * 512];
            gl_lds16(g, l);
        }
        __syncthreads();

        bf16x8 af[4], bfg[NI];
#pragma unroll
        for (int mi = 0; mi < 4; mi++)
            af[mi] = __builtin_bit_cast(bf16x8,
                *(const u16x8*)&As[((wm << 6) + (mi << 4) + l15) * 32 + koff]);
#pragma unroll
        for (int ni = 0; ni < NI; ni++)
            bfg[ni] = __builtin_bit_cast(bf16x8,
                *(const u16x8*)&Bs[(wn * WN + (ni << 4) + l15) * 32 + koff]);

#pragma unroll
        for (int mi = 0; mi < 4; mi++)
#pragma unroll
            for (int ni = 0; ni < NI; ni++)
                acc[mi][ni] = __builtin_amdgcn_mfma_f32_16x16x32_bf16(
                    af[mi], bfg[ni], acc[mi][ni], 0, 0, 0);
    }

    // epilogue: C/D layout col=lane&15, row=(lane>>4)*4+reg
    const int r0 = (lane >> 4) << 2;
    float bv[NI];
    if (EPI == 1) {
#pragma unroll
        for (int ni = 0; ni < NI; ni++)
            bv[ni] = bias[bn * BN + wn * WN + ni * 16 + l15];
    }
#pragma unroll
    for (int mi = 0; mi < 4; mi++) {
#pragma unroll
        for (int ni = 0; ni < NI; ni++) {
            const int row = bm * 128 + wm * 64 + mi * 16 + r0;
            const int col = bn * BN + wn * WN + ni * 16 + l15;
#pragma unroll
            for (int r = 0; r < 4; r++) {
                float v = acc[mi][ni][r];
                if (EPI == 0) {
                    ((float*)outp)[(size_t)(row + r) * ACTION + col] = sig500(v);
                } else {
                    ((u16*)outp)[(size_t)(row + r) * NNODES + col] =
                        f2bf(ftanh(v + bv[ni]));
                }
            }
        }
    }
}

extern "C" void kernel_launch(void* const* d_in, const int* in_sizes, int n_in,
                              void* d_out, int out_size, void* d_ws, size_t ws_size,
                              hipStream_t stream) {
    const float* state = (const float*)d_in[0];
    const float* W     = (const float*)d_in[1];
    const float* b     = (const float*)d_in[2];
    const float* Wf    = (const float*)d_in[3];
    const int*   idx   = (const int*)  d_in[4];
    float* out = (float*)d_out;

    u16* sbf = (u16*)d_ws;                         // 8192*352 bf16
    u16* wg  = sbf + (size_t)BATCH * KPAD;         // 256*352
    u16* y   = wg  + (size_t)NNODES * KPAD;        // 8192*256
    u16* wfb = y   + (size_t)BATCH * NNODES;       // 4096*256

    build_wg  <<<NNODES / 8, 256, 0, stream>>>(W, idx, wg);
    conv_state<<<BATCH * 88 / 256, 256, 0, stream>>>(state, sbf);
    conv_wf   <<<ACTION * NNODES / 1024, 256, 0, stream>>>(Wf, wfb);
    gemm_mfma<KPAD, 1, 64><<<dim3(BATCH / 128, NNODES / 64), 256, 0, stream>>>(
        sbf, wg, (void*)y, b);
    gemm_mfma<256, 0, 128><<<dim3(BATCH / 128, ACTION / 128), 256, 0, stream>>>(
        y, wfb, (void*)out, nullptr);
}

// Round 4
// 177.620 us; speedup vs baseline: 1.0724x; 1.0259x over previous
//
#include <hip/hip_runtime.h>
#include <hip/hip_bf16.h>
#include <cmath>

#define ENTRIES 27
#define ACTION  4096
#define BATCH   8192
#define SDIM    322
#define KPAD    352      // 322 padded to multiple of 32
#define NNODES  256

typedef unsigned short u16;
typedef u16 u16x4 __attribute__((ext_vector_type(4)));
typedef u16 u16x8 __attribute__((ext_vector_type(8)));
typedef __bf16 bf16x8 __attribute__((ext_vector_type(8)));
typedef float floatx4 __attribute__((ext_vector_type(4)));

__device__ __forceinline__ u16 f2bf(float f) {
    unsigned u = __builtin_bit_cast(unsigned, f);
    unsigned r = (u + 0x7FFFu + ((u >> 16) & 1u)) >> 16;   // RNE
    return (u16)r;
}

// fast 500*sigmoid(v)
__device__ __forceinline__ float sig500(float v) {
    return __fdividef(500.0f, 1.0f + __expf(-v));
}
// fast tanh: 1 - 2/(e^{2x}+1)
__device__ __forceinline__ float ftanh(float x) {
    return 1.0f - __fdividef(2.0f, __expf(2.0f * x) + 1.0f);
}

// async global->LDS, 16 B per lane; LDS dest = wave-uniform base + lane*16
__device__ __forceinline__ void gl_lds16(const u16* g, u16* l) {
    __builtin_amdgcn_global_load_lds(
        (const __attribute__((address_space(1))) unsigned int*)g,
        (__attribute__((address_space(3))) unsigned int*)l, 16, 0, 0);
}

// ---------------------------------------------------------------------------
// Fused prep:
//   blocks [0,32):      Wg[256,KPAD] bf16 scatter-build (8 nodes/block)
//   blocks [32,1056):   Wf f32[4096,256] -> bf16
//   blocks [1056,3872): state f32[8192,322] -> bf16 [8192,KPAD] zero-padded
// ---------------------------------------------------------------------------
#define PREP_WF0   32
#define PREP_ST0   1056
#define PREP_TOT   3872

__global__ __launch_bounds__(256) void prep_kernel(
    const float* __restrict__ W, const int* __restrict__ idx,
    const float* __restrict__ wf, const float* __restrict__ state,
    u16* __restrict__ wg, u16* __restrict__ wfb, u16* __restrict__ sbf)
{
    const int tid = threadIdx.x;
    const int bid = blockIdx.x;

    if (bid < PREP_WF0) {
        // ---- build Wg (duplicates sum via LDS atomics) ----
        __shared__ float rows[8 * KPAD];               // 11264 B
        for (int i = tid; i < 8 * KPAD; i += 256) rows[i] = 0.f;
        __syncthreads();
        if (tid < 8 * ENTRIES) {                       // 216 active
            const int nl = tid / ENTRIES;
            const int e  = tid - nl * ENTRIES;
            const int n  = bid * 8 + nl;
            atomicAdd(&rows[nl * KPAD + idx[n * ENTRIES + e]],
                      W[n * ENTRIES + e]);
        }
        __syncthreads();
        for (int i = tid; i < 8 * KPAD; i += 256)
            wg[(size_t)bid * 8 * KPAD + i] = f2bf(rows[i]);
    } else if (bid < PREP_ST0) {
        // ---- Wf f32 -> bf16 ----
        const int i0 = ((bid - PREP_WF0) * 256 + tid) * 4;
        floatx4 v = *(const floatx4*)(wf + i0);
        u16x4 r;
        r.x = f2bf(v.x); r.y = f2bf(v.y); r.z = f2bf(v.z); r.w = f2bf(v.w);
        *(u16x4*)(wfb + i0) = r;
    } else {
        // ---- state f32 -> bf16 padded ----
        const int t   = (bid - PREP_ST0) * 256 + tid;  // over 8192 * 88
        const int row = t / 88;
        const int c0  = (t - row * 88) * 4;
        const float* sp = state + (size_t)row * SDIM;
        u16x4 r;
#pragma unroll
        for (int q = 0; q < 4; q++) {
            const int c = c0 + q;
            float v = (c < SDIM) ? sp[c] : 0.f;
            ((u16*)&r)[q] = f2bf(v);
        }
        *(u16x4*)(sbf + (size_t)row * KPAD + c0) = r;
    }
}

// ---------------------------------------------------------------------------
// GEMM: C[m,n] = f( sum_k A[m,k]*B[n,k] ), both K-major bf16.
// Tile 128 x BN, BK=32, 4 waves as 2x2 (each 64 x BN/2),
// mfma_f32_16x16x32_bf16, global_load_lds width-16 staging (m97 structure).
// EPI=0: f32 out [.., ACTION] = 500*sigmoid(acc)
// EPI=1: bf16 out [.., NNODES] = tanh(acc + bias[n])
// ---------------------------------------------------------------------------
template<int KDIM, int EPI, int BN>
__global__ __launch_bounds__(256) void gemm_mfma(
    const u16* __restrict__ A, const u16* __restrict__ B,
    void* __restrict__ outp, const float* __restrict__ bias)
{
    constexpr int NI  = BN / 32;         // per-wave 16-col tiles (2 n-waves)
    constexpr int WN  = BN / 2;          // per-wave n extent
    constexpr int ACH = 8;               // A chunks of 1024 B (16 rows x 32 cols)
    constexpr int BCH = BN / 16;         // B chunks

    __shared__ u16 As[128 * 32];
    __shared__ u16 Bs[BN * 32];

    const int bm   = blockIdx.x;
    const int bn   = blockIdx.y;
    const int tid  = threadIdx.x;
    const int lane = tid & 63;
    const int wave = tid >> 6;
    const int wm   = wave & 1;
    const int wn   = wave >> 1;
    const int l15  = lane & 15;
    const int koff = (lane >> 4) << 3;

    floatx4 acc[4][NI];
#pragma unroll
    for (int mi = 0; mi < 4; mi++)
#pragma unroll
        for (int ni = 0; ni < NI; ni++)
            acc[mi][ni] = (floatx4){0.f, 0.f, 0.f, 0.f};

    // staging: chunk = 16 rows x 32 cols = 1024 B; lane -> row +(l>>2), k (l&3)*8
    const int crow = lane >> 2;
    const int ckel = (lane & 3) << 3;

#pragma unroll
    for (int kk = 0; kk < KDIM; kk += 32) {
        __syncthreads();
#pragma unroll
        for (int c = wave; c < ACH + BCH; c += 4) {
            const bool isA = c < ACH;
            const int  cr  = isA ? c : c - ACH;
            const int  row = cr * 16 + crow;
            const u16* g = isA
                ? (A + ((size_t)bm * 128 + row) * KDIM + kk + ckel)
                : (B + ((size_t)bn * BN  + row) * KDIM + kk + ckel);
            u16* l = isA ? &As[cr * 512] : &Bs[cr * 512];
            gl_lds16(g, l);
        }
        __syncthreads();

        bf16x8 af[4], bfg[NI];
#pragma unroll
        for (int mi = 0; mi < 4; mi++)
            af[mi] = __builtin_bit_cast(bf16x8,
                *(const u16x8*)&As[((wm << 6) + (mi << 4) + l15) * 32 + koff]);
#pragma unroll
        for (int ni = 0; ni < NI; ni++)
            bfg[ni] = __builtin_bit_cast(bf16x8,
                *(const u16x8*)&Bs[(wn * WN + (ni << 4) + l15) * 32 + koff]);

#pragma unroll
        for (int mi = 0; mi < 4; mi++)
#pragma unroll
            for (int ni = 0; ni < NI; ni++)
                acc[mi][ni] = __builtin_amdgcn_mfma_f32_16x16x32_bf16(
                    af[mi], bfg[ni], acc[mi][ni], 0, 0, 0);
    }

    // epilogue: C/D layout col=lane&15, row=(lane>>4)*4+reg
    const int r0 = (lane >> 4) << 2;
    float bv[NI];
    if (EPI == 1) {
#pragma unroll
        for (int ni = 0; ni < NI; ni++)
            bv[ni] = bias[bn * BN + wn * WN + ni * 16 + l15];
    }
#pragma unroll
    for (int mi = 0; mi < 4; mi++) {
#pragma unroll
        for (int ni = 0; ni < NI; ni++) {
            const int row = bm * 128 + wm * 64 + mi * 16 + r0;
            const int col = bn * BN + wn * WN + ni * 16 + l15;
#pragma unroll
            for (int r = 0; r < 4; r++) {
                float v = acc[mi][ni][r];
                if (EPI == 0) {
                    ((float*)outp)[(size_t)(row + r) * ACTION + col] = sig500(v);
                } else {
                    ((u16*)outp)[(size_t)(row + r) * NNODES + col] =
                        f2bf(ftanh(v + bv[ni]));
                }
            }
        }
    }
}

extern "C" void kernel_launch(void* const* d_in, const int* in_sizes, int n_in,
                              void* d_out, int out_size, void* d_ws, size_t ws_size,
                              hipStream_t stream) {
    const float* state = (const float*)d_in[0];
    const float* W     = (const float*)d_in[1];
    const float* b     = (const float*)d_in[2];
    const float* Wf    = (const float*)d_in[3];
    const int*   idx   = (const int*)  d_in[4];
    float* out = (float*)d_out;

    u16* sbf = (u16*)d_ws;                         // 8192*352 bf16
    u16* wg  = sbf + (size_t)BATCH * KPAD;         // 256*352
    u16* y   = wg  + (size_t)NNODES * KPAD;        // 8192*256
    u16* wfb = y   + (size_t)BATCH * NNODES;       // 4096*256

    prep_kernel<<<PREP_TOT, 256, 0, stream>>>(W, idx, Wf, state, wg, wfb, sbf);
    gemm_mfma<KPAD, 1, 64><<<dim3(BATCH / 128, NNODES / 64), 256, 0, stream>>>(
        sbf, wg, (void*)y, b);
    gemm_mfma<256, 0, 128><<<dim3(BATCH / 128, ACTION / 128), 256, 0, stream>>>(
        y, wfb, (void*)out, nullptr);
}